// Round 15
// baseline (233.735 us; speedup 1.0000x reference)
//
#include <hip/hip_runtime.h>
#include <hip/hip_bf16.h>

#define EPS 1e-5f
constexpr int BN = 131072;
constexpr int NBKT = 32;
constexpr int NTILE = BN/64;           // 2048 tiles
constexpr int TILE_ELEMS = 256*64;     // 16384 bf16 per tile (32 KB)

typedef __attribute__((ext_vector_type(8))) short bf16x8;
typedef __attribute__((ext_vector_type(4))) float f32x4;

// ---- workspace layout (float offsets) ----
constexpr size_t OFF_H   = 0;
constexpr size_t OFF_HH  = OFF_H  + (size_t)BN*10;
constexpr size_t OFF_M1  = OFF_HH + (size_t)BN*10;
constexpr size_t OFF_S2  = OFF_M1 + 65;
constexpr size_t OFF_M3  = OFF_S2 + 512;
constexpr size_t OFF_S4  = OFF_M3 + 65;
constexpr size_t OFF_WA1 = OFF_S4 + 512;
constexpr size_t OFF_BA1 = OFF_WA1 + 1280;
constexpr size_t OFF_WA2 = OFF_BA1 + 128;
constexpr size_t OFF_BA2 = OFF_WA2 + 1280;
constexpr size_t OFF_SC2 = OFF_BA2 + 128;
constexpr size_t OFF_TC2 = OFF_SC2 + 256;
constexpr size_t OFF_SC4 = OFF_TC2 + 256;
constexpr size_t OFF_TC4 = OFF_SC4 + 256;
constexpr size_t OFF_WB1 = OFF_TC4 + 256;
constexpr size_t OFF_BB1 = OFF_WB1 + 32768;
constexpr size_t OFF_WB2 = OFF_BB1 + 256;
constexpr size_t OFF_BB2 = OFF_WB2 + 32768;
constexpr size_t OFF_P1  = OFF_BB2 + 256;             // 1024x65 moment partials
constexpr size_t OFF_P3  = OFF_P1 + 1024*65;
constexpr size_t OFF_S2B = OFF_P3 + 1024*65;          // NBKT x 512 bucket stats
constexpr size_t OFF_S4B = OFF_S2B + (size_t)NBKT*512;
constexpr size_t OFF_WT1 = OFF_S4B + (size_t)NBKT*512;
constexpr size_t OFF_WT2 = OFF_WT1 + 16384;
constexpr size_t OFF_END = OFF_WT2 + 16384;
constexpr size_t OFF_Z_BYTES = ((OFF_END*4 + 255) & ~(size_t)255); // tiled z
constexpr size_t WS_NEED = OFF_Z_BYTES + (size_t)NTILE*TILE_ELEMS*2;

__device__ __forceinline__ float wsum(float v){
  v += __shfl_down(v, 32);
  v += __shfl_down(v, 16);
  v += __shfl_down(v, 8);
  v += __shfl_down(v, 4);
  v += __shfl_down(v, 2);
  v += __shfl_down(v, 1);
  return v;
}

__device__ __forceinline__ unsigned pk_bf16(float a, float b){
  union { __hip_bfloat16 h[2]; unsigned u; } cv;
  cv.h[0] = __float2bfloat16(a);
  cv.h[1] = __float2bfloat16(b);
  return cv.u;
}

__device__ __forceinline__ unsigned short bf16_1(float a){
  union { __hip_bfloat16 h; unsigned short u; } cv;
  cv.h = __float2bfloat16(a);
  return cv.u;
}

__device__ __forceinline__ float bf16_to_f(unsigned short u){
  return __uint_as_float(((unsigned)u) << 16);
}
__device__ __forceinline__ float bf16_lo(unsigned u){ return __uint_as_float(u << 16); }
__device__ __forceinline__ float bf16_hi(unsigned u){ return __uint_as_float(u & 0xffff0000u); }

// attention on a 10-vector: softmax over q (axis=1!) per column k
__device__ __forceinline__ void attn10(const float* xr, float cqk, float cvo, float* y){
  #pragma unroll
  for (int q=0;q<10;q++) y[q] = 0.f;
  #pragma unroll
  for (int k=0;k<10;k++){
    float t = cqk * xr[k];
    float m = t*xr[0];
    #pragma unroll
    for (int q=1;q<10;q++) m = fmaxf(m, t*xr[q]);
    float ex[10]; float s = 0.f;
    #pragma unroll
    for (int q=0;q<10;q++){ ex[q] = __expf(t*xr[q]-m); s += ex[q]; }
    float f = xr[k]/s;
    #pragma unroll
    for (int q=0;q<10;q++) y[q] += ex[q]*f;
  }
  #pragma unroll
  for (int q=0;q<10;q++) y[q] *= cvo;
}

// block-level moment reduction (4 waves)
__device__ __forceinline__ void moments_block(const float* y, float (*red)[65],
                                              float* Pb, int t){
  int lane = t & 63, w = t >> 6;
  #pragma unroll
  for (int i=0;i<10;i++){
    float v = wsum(y[i]);
    if (lane==0) red[w][i] = v;
  }
  #pragma unroll
  for (int i=0;i<10;i++){
    #pragma unroll
    for (int j=i;j<10;j++){
      float v = wsum(y[i]*y[j]);
      if (lane==0) red[w][10 + 10*i - i*(i-1)/2 + (j-i)] = v;
    }
  }
  __syncthreads();
  if (t < 65)
    Pb[(size_t)blockIdx.x*65 + t] = red[0][t]+red[1][t]+red[2][t]+red[3][t];
}

// legacy atomic moments (fallback path only)
__device__ __forceinline__ void moments10(const float* y, float* M, int lane){
  #pragma unroll
  for (int i=0;i<10;i++){
    float s = wsum(y[i]);
    if (lane==0) atomicAdd(&M[i], s);
  }
  #pragma unroll
  for (int i=0;i<10;i++){
    #pragma unroll
    for (int j=i;j<10;j++){
      int id = 10*i - i*(i-1)/2 + (j-i);
      float s = wsum(y[i]*y[j]);
      if (lane==0) atomicAdd(&M[10+id], s);
    }
  }
}

// K1: x -> attn1 -> h  (staged loads/stores + per-block moment partials)
__global__ __launch_bounds__(256) void k_attn_in(
    const float* __restrict__ x,
    const float* __restrict__ Wq, const float* __restrict__ Wk,
    const float* __restrict__ Wv, const float* __restrict__ Wo,
    float* __restrict__ h, float* __restrict__ Pb){
  __shared__ float xs[256][11];
  __shared__ float red[4][65];
  int t = threadIdx.x;
  size_t base = (size_t)blockIdx.x*2560;
  for (int idx=t; idx<2560; idx+=256) xs[idx/10][idx%10] = x[base+idx];
  float cqk=0.f, cvo=0.f;
  #pragma unroll
  for (int d=0;d<16;d++){ cqk += Wq[d]*Wk[d]; cvo += Wv[d]*Wo[d]; }
  cqk *= 0.25f;
  __syncthreads();
  float xr[10];
  #pragma unroll
  for (int q=0;q<10;q++) xr[q] = xs[t][q];
  float y[10];
  attn10(xr, cqk, cvo, y);
  #pragma unroll
  for (int q=0;q<10;q++) xs[t][q] = y[q];
  moments_block(y, red, Pb, t);   // contains a __syncthreads()
  for (int idx=t; idx<2560; idx+=256) h[base+idx] = xs[idx/10][idx%10];
}

// fold BN over (10,128) from npart moment-partials -> WT (128,10), bo (128)
// launch with 576 threads; npart % 8 == 0
__global__ void k_fold10_part(const float* __restrict__ Pb, int npart,
                              const float* __restrict__ W,
                              const float* __restrict__ bv, const float* __restrict__ g,
                              const float* __restrict__ be,
                              float* __restrict__ WT, float* __restrict__ bo){
  __shared__ float part[65][8];
  __shared__ float sM[65];
  int t = threadIdx.x;
  if (t < 520){
    int c = t>>3, k = t&7;
    int n = npart>>3;
    float acc = 0.f;
    #pragma unroll 4
    for (int i=0;i<n;i++) acc += Pb[(size_t)(k*n+i)*65 + c];
    part[c][k] = acc;
  }
  __syncthreads();
  if (t < 65){
    float a = 0.f;
    #pragma unroll
    for (int k=0;k<8;k++) a += part[t][k];
    sM[t] = a;
  }
  __syncthreads();
  int j = t;
  if (j >= 128) return;
  const float invB = 1.f/(float)BN;
  float Eh[10];
  #pragma unroll
  for (int i=0;i<10;i++) Eh[i] = sM[i]*invB;
  float wj[10];
  #pragma unroll
  for (int i=0;i<10;i++) wj[i] = W[i*128+j];
  float mu = bv[j];
  #pragma unroll
  for (int i=0;i<10;i++) mu += Eh[i]*wj[i];
  float var = 0.f;
  #pragma unroll
  for (int i=0;i<10;i++){
    #pragma unroll
    for (int l=0;l<10;l++){
      int a = i<l ? i : l, c = i<l ? l : i;
      int id = 10*a - a*(a-1)/2 + (c-a);
      float cov = sM[10+id]*invB - Eh[i]*Eh[l];
      var += wj[i]*wj[l]*cov;
    }
  }
  float s = g[j]*rsqrtf(var + EPS);
  #pragma unroll
  for (int i=0;i<10;i++) WT[j*10+i] = wj[i]*s;
  bo[j] = (bv[j]-mu)*s + be[j];
}

// legacy atomic-M fold (fallback path only)
__global__ void k_fold10_atomic(const float* __restrict__ M,
                                const float* __restrict__ W,
                                const float* __restrict__ bv, const float* __restrict__ g,
                                const float* __restrict__ be,
                                float* __restrict__ WT, float* __restrict__ bo){
  int j = threadIdx.x;
  if (j >= 128) return;
  const float invB = 1.f/(float)BN;
  float Eh[10];
  #pragma unroll
  for (int i=0;i<10;i++) Eh[i] = M[i]*invB;
  float wj[10];
  #pragma unroll
  for (int i=0;i<10;i++) wj[i] = W[i*128+j];
  float mu = bv[j];
  #pragma unroll
  for (int i=0;i<10;i++) mu += Eh[i]*wj[i];
  float var = 0.f;
  #pragma unroll
  for (int i=0;i<10;i++){
    #pragma unroll
    for (int l=0;l<10;l++){
      int a = i<l ? i : l, c = i<l ? l : i;
      int id = 10*a - a*(a-1)/2 + (c-a);
      float cov = M[10+id]*invB - Eh[i]*Eh[l];
      var += wj[i]*wj[l]*cov;
    }
  }
  float s = g[j]*rsqrtf(var + EPS);
  #pragma unroll
  for (int i=0;i<10;i++) WT[j*10+i] = wj[i]*s;
  bo[j] = (bv[j]-mu)*s + be[j];
}

// BN fold as per-column affine from NBKT bucket stats (z includes bias)
__global__ void k_fold_affine(const float* __restrict__ stats,
                              const float* __restrict__ g,
                              const float* __restrict__ be,
                              float* __restrict__ s, float* __restrict__ tt){
  int j = threadIdx.x;
  if (j >= 256) return;
  float su = 0.f, sq = 0.f;
  #pragma unroll 4
  for (int k=0;k<NBKT;k++){
    su += stats[k*512 + j];
    sq += stats[k*512 + 256 + j];
  }
  const float invB = 1.f/(float)BN;
  float mu  = su*invB;
  float var = sq*invB - mu*mu;
  float sc = g[j]*rsqrtf(var + EPS);
  s[j]  = sc;
  tt[j] = be[j] - mu*sc;
}

// transpose+convert both W (128,256) f32 -> WT (256,128) bf16 ; grid 256
__global__ __launch_bounds__(256) void k_prep_wt2(
    const float* __restrict__ W1, const float* __restrict__ W2,
    unsigned short* __restrict__ WT1, unsigned short* __restrict__ WT2){
  int g = blockIdx.x;
  const float* W = (g < 128) ? W1 : W2;
  unsigned short* WT = (g < 128) ? WT1 : WT2;
  int idx = (g & 127)*256 + threadIdx.x;
  int c = idx >> 7, k = idx & 127;
  WT[idx] = bf16_1(W[k*256 + c]);
}

// ===================== 2-slab pipelined producer (verified r14) ================
__global__ __launch_bounds__(256) void k_layer_mfma(
    const float* __restrict__ h,
    const float* __restrict__ WaT,
    const float* __restrict__ ba,
    const unsigned short* __restrict__ WT,
    const float* __restrict__ bb,
    unsigned short* __restrict__ zt,
    float* __restrict__ stats)
{
  __shared__ unsigned short h1s[2][64*128];
  __shared__ float hs[128][11];
  __shared__ float sWaT[1280];
  int t = threadIdx.x;
  int lane = t & 63, w = t >> 6;
  int ci = lane & 15, g = lane >> 4;
  size_t row0 = (size_t)blockIdx.x * 128;

  bf16x8 bfr[4][4];
  #pragma unroll
  for (int nt=0; nt<4; nt++)
    #pragma unroll
    for (int kt=0; kt<4; kt++){
      union { uint4 u; bf16x8 v; } cv;
      cv.u = *(const uint4*)(WT + (size_t)(w*64 + nt*16 + ci)*128 + kt*32 + g*8);
      bfr[nt][kt] = cv.v;
    }

  for (int idx = t; idx < 1280; idx += 256) hs[idx/10][idx%10] = h[row0*10 + idx];
  for (int idx = t; idx < 1280; idx += 256) sWaT[idx] = WaT[idx];
  __syncthreads();

  float bbv[4];
  #pragma unroll
  for (int nt=0;nt<4;nt++) bbv[nt] = bb[w*64 + nt*16 + ci];
  float cs[4] = {0,0,0,0}, cq[4] = {0,0,0,0};

  {
    int r = lane;
    int i0 = w * 32;
    float hr[10];
    #pragma unroll
    for (int l=0;l<10;l++) hr[l] = hs[r][l];
    #pragma unroll
    for (int j=0;j<4;j++){
      unsigned pk[4];
      #pragma unroll
      for (int q=0;q<4;q++){
        int i = i0 + j*8 + q*2;
        float v0 = ba[i], v1 = ba[i+1];
        #pragma unroll
        for (int l=0;l<10;l++){
          v0 = fmaf(hr[l], sWaT[i*10+l],     v0);
          v1 = fmaf(hr[l], sWaT[(i+1)*10+l], v1);
        }
        pk[q] = pk_bf16(fmaxf(v0,0.f), fmaxf(v1,0.f));
      }
      int byte = r*256 + (((i0 + j*8)*2) ^ ((r&7)<<4));
      *(uint4*)((char*)h1s[0] + byte) = make_uint4(pk[0],pk[1],pk[2],pk[3]);
    }
  }
  __syncthreads();

  f32x4 acc[4][4];
  #pragma unroll
  for (int mt=0;mt<4;mt++)
    #pragma unroll
    for (int nt=0;nt<4;nt++)
      acc[mt][nt] = (f32x4){0.f,0.f,0.f,0.f};
  #pragma unroll
  for (int mt=0; mt<4; mt++){
    int r = mt*16 + ci;
    bf16x8 af[4];
    #pragma unroll
    for (int kt=0; kt<4; kt++){
      int byte = r*256 + ((kt*64 + g*16) ^ ((r&7)<<4));
      af[kt] = *(const bf16x8*)((const char*)h1s[0] + byte);
    }
    #pragma unroll
    for (int nt=0; nt<4; nt++)
      #pragma unroll
      for (int kt=0; kt<4; kt++)
        acc[mt][nt] = __builtin_amdgcn_mfma_f32_16x16x32_bf16(
            af[kt], bfr[nt][kt], acc[mt][nt], 0, 0, 0);
  }

  {
    size_t tbase = ((size_t)blockIdx.x*2 + 0) * TILE_ELEMS;
    #pragma unroll
    for (int nt=0; nt<4; nt++){
      int c = w*64 + nt*16 + ci;
      #pragma unroll
      for (int mt=0; mt<4; mt++){
        float z0 = acc[mt][nt][0] + bbv[nt];
        float z1 = acc[mt][nt][1] + bbv[nt];
        float z2 = acc[mt][nt][2] + bbv[nt];
        float z3 = acc[mt][nt][3] + bbv[nt];
        cs[nt] += z0+z1+z2+z3;
        cq[nt] += z0*z0+z1*z1+z2*z2+z3*z3;
        *(uint2*)(zt + tbase + c*64 + mt*16 + g*4) =
            make_uint2(pk_bf16(z0,z1), pk_bf16(z2,z3));
      }
    }
  }

  {
    int r = lane;
    int i0 = w * 32;
    float hr[10];
    #pragma unroll
    for (int l=0;l<10;l++) hr[l] = hs[64 + r][l];
    #pragma unroll
    for (int j=0;j<4;j++){
      unsigned pk[4];
      #pragma unroll
      for (int q=0;q<4;q++){
        int i = i0 + j*8 + q*2;
        float v0 = ba[i], v1 = ba[i+1];
        #pragma unroll
        for (int l=0;l<10;l++){
          v0 = fmaf(hr[l], sWaT[i*10+l],     v0);
          v1 = fmaf(hr[l], sWaT[(i+1)*10+l], v1);
        }
        pk[q] = pk_bf16(fmaxf(v0,0.f), fmaxf(v1,0.f));
      }
      int byte = r*256 + (((i0 + j*8)*2) ^ ((r&7)<<4));
      *(uint4*)((char*)h1s[1] + byte) = make_uint4(pk[0],pk[1],pk[2],pk[3]);
    }
  }
  __syncthreads();

  #pragma unroll
  for (int mt=0;mt<4;mt++)
    #pragma unroll
    for (int nt=0;nt<4;nt++)
      acc[mt][nt] = (f32x4){0.f,0.f,0.f,0.f};
  #pragma unroll
  for (int mt=0; mt<4; mt++){
    int r = mt*16 + ci;
    bf16x8 af[4];
    #pragma unroll
    for (int kt=0; kt<4; kt++){
      int byte = r*256 + ((kt*64 + g*16) ^ ((r&7)<<4));
      af[kt] = *(const bf16x8*)((const char*)h1s[1] + byte);
    }
    #pragma unroll
    for (int nt=0; nt<4; nt++)
      #pragma unroll
      for (int kt=0; kt<4; kt++)
        acc[mt][nt] = __builtin_amdgcn_mfma_f32_16x16x32_bf16(
            af[kt], bfr[nt][kt], acc[mt][nt], 0, 0, 0);
  }

  {
    size_t tbase = ((size_t)blockIdx.x*2 + 1) * TILE_ELEMS;
    #pragma unroll
    for (int nt=0; nt<4; nt++){
      int c = w*64 + nt*16 + ci;
      #pragma unroll
      for (int mt=0; mt<4; mt++){
        float z0 = acc[mt][nt][0] + bbv[nt];
        float z1 = acc[mt][nt][1] + bbv[nt];
        float z2 = acc[mt][nt][2] + bbv[nt];
        float z3 = acc[mt][nt][3] + bbv[nt];
        cs[nt] += z0+z1+z2+z3;
        cq[nt] += z0*z0+z1*z1+z2*z2+z3*z3;
        *(uint2*)(zt + tbase + c*64 + mt*16 + g*4) =
            make_uint2(pk_bf16(z0,z1), pk_bf16(z2,z3));
      }
    }
  }

  #pragma unroll
  for (int nt=0; nt<4; nt++){
    float s1 = cs[nt], s2 = cq[nt];
    s1 += __shfl_down(s1, 32); s1 += __shfl_down(s1, 16);
    s2 += __shfl_down(s2, 32); s2 += __shfl_down(s2, 16);
    if (lane < 16){
      int bkt = blockIdx.x & (NBKT-1);
      int c = w*64 + nt*16 + ci;
      atomicAdd(&stats[bkt*512 + c],       s1);
      atomicAdd(&stats[bkt*512 + 256 + c], s2);
    }
  }
}

// ===================== consume v3: 512 rows/block, 2 rows/thread ==============
// zs chunk layout: [32 cols][512 rows] u16, write-side XOR (cl&7)<<4 on 16B chunks
__global__ __launch_bounds__(256) void k_consume_mid(
    const unsigned short* __restrict__ zt,
    const float* __restrict__ s_g, const float* __restrict__ t_g,
    const float* __restrict__ Wc,  const float* __restrict__ bc,
    const float* __restrict__ Wq, const float* __restrict__ Wk,
    const float* __restrict__ Wv, const float* __restrict__ Wo,
    float* __restrict__ hh, float* __restrict__ Pb){
  __shared__ __align__(16) unsigned short zs[32*512];  // 32 KB
  __shared__ __align__(16) float sWc[256*12];          // 12 KB padded
  __shared__ float ss[256], st[256];
  __shared__ float red[4][65];
  int t = threadIdx.x;
  for (int idx=t; idx<2560; idx+=256) sWc[(idx/10)*12 + (idx%10)] = Wc[idx];
  ss[t] = s_g[t]; st[t] = t_g[t];
  size_t b0 = (size_t)blockIdx.x*512;

  float z3a[10], z3b[10];
  #pragma unroll
  for (int l=0;l<10;l++){ z3a[l] = bc[l]; z3b[l] = bc[l]; }

  int q8 = t >> 5, cl0 = t & 31;       // load role: tile q8, column cl0
  size_t src_base = ((size_t)blockIdx.x*8 + q8)*TILE_ELEMS + (size_t)cl0*64;
  int sbits = (cl0 & 7) << 4;
  char* wbase = (char*)zs + cl0*1024;

  uint4 pf[8];
  {
    const uint4* s = (const uint4*)(zt + src_base);
    #pragma unroll
    for (int k=0;k<8;k++) pf[k] = s[k];
  }
  for (int cc=0; cc<8; cc++){
    __syncthreads();     // zs free (covers sWc/ss on first iter)
    #pragma unroll
    for (int k=0;k<8;k++)
      *(uint4*)(wbase + ((q8*128 + k*16) ^ sbits)) = pf[k];
    if (cc < 7){
      const uint4* s = (const uint4*)(zt + src_base + (size_t)(cc+1)*2048);
      #pragma unroll
      for (int k=0;k<8;k++) pf[k] = s[k];
    }
    __syncthreads();
    #pragma unroll 4
    for (int cl=0; cl<32; cl++){
      int c = cc*32 + cl;
      unsigned u = *(const unsigned*)((const char*)zs + cl*1024 + ((4*t) ^ ((cl&7)<<4)));
      float ha = fmaxf(fmaf(ss[c], bf16_lo(u), st[c]), 0.f);
      float hb = fmaxf(fmaf(ss[c], bf16_hi(u), st[c]), 0.f);
      const float4* wr = (const float4*)&sWc[c*12];
      float4 w0 = wr[0];
      float4 w1 = wr[1];
      float2 w2 = *(const float2*)&sWc[c*12 + 8];
      z3a[0]=fmaf(ha,w0.x,z3a[0]); z3b[0]=fmaf(hb,w0.x,z3b[0]);
      z3a[1]=fmaf(ha,w0.y,z3a[1]); z3b[1]=fmaf(hb,w0.y,z3b[1]);
      z3a[2]=fmaf(ha,w0.z,z3a[2]); z3b[2]=fmaf(hb,w0.z,z3b[2]);
      z3a[3]=fmaf(ha,w0.w,z3a[3]); z3b[3]=fmaf(hb,w0.w,z3b[3]);
      z3a[4]=fmaf(ha,w1.x,z3a[4]); z3b[4]=fmaf(hb,w1.x,z3b[4]);
      z3a[5]=fmaf(ha,w1.y,z3a[5]); z3b[5]=fmaf(hb,w1.y,z3b[5]);
      z3a[6]=fmaf(ha,w1.z,z3a[6]); z3b[6]=fmaf(hb,w1.z,z3b[6]);
      z3a[7]=fmaf(ha,w1.w,z3a[7]); z3b[7]=fmaf(hb,w1.w,z3b[7]);
      z3a[8]=fmaf(ha,w2.x,z3a[8]); z3b[8]=fmaf(hb,w2.x,z3b[8]);
      z3a[9]=fmaf(ha,w2.y,z3a[9]); z3b[9]=fmaf(hb,w2.y,z3b[9]);
    }
  }

  float cqk=0.f, cvo=0.f;
  #pragma unroll
  for (int d=0;d<16;d++){ cqk += Wq[d]*Wk[d]; cvo += Wv[d]*Wo[d]; }
  cqk *= 0.25f;
  float ya[10], yb[10];
  attn10(z3a, cqk, cvo, ya);
  attn10(z3b, cqk, cvo, yb);

  __syncthreads();    // zs reads done; reuse as hh staging
  float* hhs = (float*)zs;   // 512*10 floats = 20 KB
  #pragma unroll
  for (int q=0;q<10;q++){ hhs[(2*t)*10+q] = ya[q]; hhs[(2*t+1)*10+q] = yb[q]; }

  // moments over both rows
  {
    int lane = t & 63, w = t >> 6;
    #pragma unroll
    for (int i=0;i<10;i++){
      float v = wsum(ya[i] + yb[i]);
      if (lane==0) red[w][i] = v;
    }
    #pragma unroll
    for (int i=0;i<10;i++){
      #pragma unroll
      for (int j=i;j<10;j++){
        float v = wsum(ya[i]*ya[j] + yb[i]*yb[j]);
        if (lane==0) red[w][10 + 10*i - i*(i-1)/2 + (j-i)] = v;
      }
    }
  }
  __syncthreads();
  if (t < 65)
    Pb[(size_t)blockIdx.x*65 + t] = red[0][t]+red[1][t]+red[2][t]+red[3][t];
  for (int idx=t; idx<5120; idx+=256)
    hh[b0*10 + idx] = hhs[idx];
}

// consume v3 out: 512 rows/block, 2 rows/thread
__global__ __launch_bounds__(256) void k_consume_out(
    const unsigned short* __restrict__ zt,
    const float* __restrict__ s_g, const float* __restrict__ t_g,
    const float* __restrict__ Wc,  const float* __restrict__ bc,
    float* __restrict__ out){
  __shared__ __align__(16) unsigned short zs[32*512];
  __shared__ __align__(8) float sWo[512];   // [c][2]
  __shared__ float ss[256], st[256];
  int t = threadIdx.x;
  sWo[t] = Wc[t]; sWo[256+t] = Wc[256+t];
  ss[t] = s_g[t]; st[t] = t_g[t];
  size_t b0 = (size_t)blockIdx.x*512;
  float o0a = bc[0], o1a = bc[1];
  float o0b = bc[0], o1b = bc[1];
  int q8 = t >> 5, cl0 = t & 31;
  size_t src_base = ((size_t)blockIdx.x*8 + q8)*TILE_ELEMS + (size_t)cl0*64;
  int sbits = (cl0 & 7) << 4;
  char* wbase = (char*)zs + cl0*1024;
  uint4 pf[8];
  {
    const uint4* s = (const uint4*)(zt + src_base);
    #pragma unroll
    for (int k=0;k<8;k++) pf[k] = s[k];
  }
  for (int cc=0; cc<8; cc++){
    __syncthreads();
    #pragma unroll
    for (int k=0;k<8;k++)
      *(uint4*)(wbase + ((q8*128 + k*16) ^ sbits)) = pf[k];
    if (cc < 7){
      const uint4* s = (const uint4*)(zt + src_base + (size_t)(cc+1)*2048);
      #pragma unroll
      for (int k=0;k<8;k++) pf[k] = s[k];
    }
    __syncthreads();
    #pragma unroll 8
    for (int cl=0; cl<32; cl++){
      int c = cc*32 + cl;
      unsigned u = *(const unsigned*)((const char*)zs + cl*1024 + ((4*t) ^ ((cl&7)<<4)));
      float ha = fmaxf(fmaf(ss[c], bf16_lo(u), st[c]), 0.f);
      float hb = fmaxf(fmaf(ss[c], bf16_hi(u), st[c]), 0.f);
      float2 wv = *(const float2*)&sWo[c*2];
      o0a = fmaf(ha, wv.x, o0a); o1a = fmaf(ha, wv.y, o1a);
      o0b = fmaf(hb, wv.x, o0b); o1b = fmaf(hb, wv.y, o1b);
    }
  }
  *(float4*)(out + (b0 + 2*t)*2) = make_float4(o0a, o1a, o0b, o1b);
}

// ===================== slow fallback path (round-0 style) =====================
__global__ void k_fold_big(const float* __restrict__ stats,
                           const float* __restrict__ W,
                           const float* __restrict__ bv, const float* __restrict__ g,
                           const float* __restrict__ be,
                           float* __restrict__ Wf, float* __restrict__ bf){
  int j = blockIdx.x*256 + threadIdx.x;
  if (j >= 256) return;
  const float invB = 1.f/(float)BN;
  float mu  = stats[j]*invB;
  float var = stats[256+j]*invB - mu*mu;
  float s = g[j]*rsqrtf(var + EPS);
  bf[j] = (bv[j]-mu)*s + be[j];
  for (int i=0;i<128;i++) Wf[i*256+j] = W[i*256+j]*s;
}

__global__ __launch_bounds__(256) void k_mid(
    const float* __restrict__ h,
    const float* __restrict__ WaT, const float* __restrict__ ba,
    const float* __restrict__ Wb,  const float* __restrict__ bb,
    float* __restrict__ stats){
  int b = blockIdx.x*256 + threadIdx.x;
  if (b >= BN) return;
  float hr[10];
  #pragma unroll
  for (int l=0;l<10;l++) hr[l] = h[(size_t)b*10+l];
  int lane = threadIdx.x & 63;
  for (int jc=0;jc<4;jc++){
    float acc[64];
    #pragma unroll
    for (int j=0;j<64;j++) acc[j] = bb[jc*64+j];
    for (int i=0;i<128;i++){
      float h1 = ba[i];
      #pragma unroll
      for (int l=0;l<10;l++) h1 += hr[l]*WaT[i*10+l];
      h1 = fmaxf(h1, 0.f);
      const float* __restrict__ w = &Wb[i*256 + jc*64];
      #pragma unroll
      for (int j=0;j<64;j++) acc[j] += h1*w[j];
    }
    #pragma unroll
    for (int j=0;j<64;j++){
      float s1 = wsum(acc[j]);
      float s2 = wsum(acc[j]*acc[j]);
      if (lane==0){
        atomicAdd(&stats[jc*64+j], s1);
        atomicAdd(&stats[256+jc*64+j], s2);
      }
    }
  }
}

__global__ __launch_bounds__(256) void k_mid2(
    const float* __restrict__ h,
    const float* __restrict__ WaT, const float* __restrict__ ba,
    const float* __restrict__ Wbf, const float* __restrict__ bbf,
    const float* __restrict__ Wc,  const float* __restrict__ bc,
    const float* __restrict__ Wq, const float* __restrict__ Wk,
    const float* __restrict__ Wv, const float* __restrict__ Wo,
    float* __restrict__ hh, float* __restrict__ M){
  int b = blockIdx.x*256 + threadIdx.x;
  if (b >= BN) return;
  float hr[10];
  #pragma unroll
  for (int l=0;l<10;l++) hr[l] = h[(size_t)b*10+l];
  float z3[10];
  #pragma unroll
  for (int l=0;l<10;l++) z3[l] = bc[l];
  for (int jc=0;jc<4;jc++){
    float acc[64];
    #pragma unroll
    for (int j=0;j<64;j++) acc[j] = bbf[jc*64+j];
    for (int i=0;i<128;i++){
      float h1 = ba[i];
      #pragma unroll
      for (int l=0;l<10;l++) h1 += hr[l]*WaT[i*10+l];
      h1 = fmaxf(h1, 0.f);
      const float* __restrict__ w = &Wbf[i*256 + jc*64];
      #pragma unroll
      for (int j=0;j<64;j++) acc[j] += h1*w[j];
    }
    #pragma unroll
    for (int j=0;j<64;j++){
      float h2 = fmaxf(acc[j], 0.f);
      const float* __restrict__ wc = &Wc[(jc*64+j)*10];
      #pragma unroll
      for (int l=0;l<10;l++) z3[l] += h2*wc[l];
    }
  }
  float cqk=0.f, cvo=0.f;
  #pragma unroll
  for (int d=0;d<16;d++){ cqk += Wq[d]*Wk[d]; cvo += Wv[d]*Wo[d]; }
  cqk *= 0.25f;
  float y[10];
  attn10(z3, cqk, cvo, y);
  #pragma unroll
  for (int q=0;q<10;q++) hh[(size_t)b*10+q] = y[q];
  moments10(y, M, threadIdx.x & 63);
}

__global__ __launch_bounds__(256) void k_out(
    const float* __restrict__ h,
    const float* __restrict__ WaT, const float* __restrict__ ba,
    const float* __restrict__ Wbf, const float* __restrict__ bbf,
    const float* __restrict__ Wc,  const float* __restrict__ bc,
    float* __restrict__ out){
  int b = blockIdx.x*256 + threadIdx.x;
  if (b >= BN) return;
  float hr[10];
  #pragma unroll
  for (int l=0;l<10;l++) hr[l] = h[(size_t)b*10+l];
  float o0 = bc[0], o1 = bc[1];
  for (int jc=0;jc<4;jc++){
    float acc[64];
    #pragma unroll
    for (int j=0;j<64;j++) acc[j] = bbf[jc*64+j];
    for (int i=0;i<128;i++){
      float h4 = ba[i];
      #pragma unroll
      for (int l=0;l<10;l++) h4 += hr[l]*WaT[i*10+l];
      h4 = fmaxf(h4, 0.f);
      const float* __restrict__ w = &Wbf[i*256 + jc*64];
      #pragma unroll
      for (int j=0;j<64;j++) acc[j] += h4*w[j];
    }
    #pragma unroll
    for (int j=0;j<64;j++){
      float h5 = fmaxf(acc[j], 0.f);
      o0 += h5*Wc[(jc*64+j)*2];
      o1 += h5*Wc[(jc*64+j)*2+1];
    }
  }
  out[(size_t)b*2]   = o0;
  out[(size_t)b*2+1] = o1;
}

extern "C" void kernel_launch(void* const* d_in, const int* in_sizes, int n_in,
                              void* d_out, int out_size, void* d_ws, size_t ws_size,
                              hipStream_t stream){
  const float* x   = (const float*)d_in[0];
  const float* Wq1 = (const float*)d_in[1];
  const float* Wk1 = (const float*)d_in[2];
  const float* Wv1 = (const float*)d_in[3];
  const float* Wo1 = (const float*)d_in[4];
  const float* Wq2 = (const float*)d_in[5];
  const float* Wk2 = (const float*)d_in[6];
  const float* Wv2 = (const float*)d_in[7];
  const float* Wo2 = (const float*)d_in[8];
  const float* W1a = (const float*)d_in[9];  const float* b1a = (const float*)d_in[10];
  const float* g1a = (const float*)d_in[11]; const float* be1a= (const float*)d_in[12];
  const float* W1b = (const float*)d_in[13]; const float* b1b = (const float*)d_in[14];
  const float* g1b = (const float*)d_in[15]; const float* be1b= (const float*)d_in[16];
  const float* W1c = (const float*)d_in[17]; const float* b1c = (const float*)d_in[18];
  const float* W2a = (const float*)d_in[19]; const float* b2a = (const float*)d_in[20];
  const float* g2a = (const float*)d_in[21]; const float* be2a= (const float*)d_in[22];
  const float* W2b = (const float*)d_in[23]; const float* b2b = (const float*)d_in[24];
  const float* g2b = (const float*)d_in[25]; const float* be2b= (const float*)d_in[26];
  const float* W2c = (const float*)d_in[27]; const float* b2c = (const float*)d_in[28];

  float* f   = (float*)d_ws;
  float* h   = f + OFF_H;
  float* hh  = f + OFF_HH;
  float* M1  = f + OFF_M1;
  float* S2  = f + OFF_S2;
  float* M3  = f + OFF_M3;
  float* S4  = f + OFF_S4;
  float* WA1 = f + OFF_WA1; float* BA1 = f + OFF_BA1;
  float* WA2 = f + OFF_WA2; float* BA2 = f + OFF_BA2;
  float* SC2 = f + OFF_SC2; float* TC2 = f + OFF_TC2;
  float* SC4 = f + OFF_SC4; float* TC4 = f + OFF_TC4;
  float* WB1 = f + OFF_WB1; float* BB1 = f + OFF_BB1;
  float* WB2 = f + OFF_WB2; float* BB2 = f + OFF_BB2;
  float* P1  = f + OFF_P1;  float* P3  = f + OFF_P3;
  float* S2B = f + OFF_S2B; float* S4B = f + OFF_S4B;
  unsigned short* WT1 = (unsigned short*)(f + OFF_WT1);
  unsigned short* WT2 = (unsigned short*)(f + OFF_WT2);
  unsigned short* ZT = (unsigned short*)((char*)d_ws + OFF_Z_BYTES);

  dim3 blk(256);
  dim3 grid256(BN/256);   // 512
  dim3 grid128(BN/128);   // 1024
  dim3 grid512(BN/512);   // 256

  if (ws_size >= WS_NEED){
    hipMemsetAsync(S2B, 0, (size_t)2*NBKT*512*sizeof(float), stream);
    k_prep_wt2<<<256,blk,0,stream>>>(W1b, W2b, WT1, WT2);
    k_attn_in<<<grid256,blk,0,stream>>>(x, Wq1,Wk1,Wv1,Wo1, h, P1);
    k_fold10_part<<<1,576,0,stream>>>(P1, 512, W1a,b1a,g1a,be1a, WA1,BA1);
    k_layer_mfma<<<grid128,blk,0,stream>>>(h, WA1,BA1, WT1,b1b, ZT, S2B);
    k_fold_affine<<<1,256,0,stream>>>(S2B, g1b, be1b, SC2, TC2);
    k_consume_mid<<<grid512,blk,0,stream>>>(ZT, SC2,TC2, W1c,b1c,
                                            Wq2,Wk2,Wv2,Wo2, hh, P3);
    k_fold10_part<<<1,576,0,stream>>>(P3, 256, W2a,b2a,g2a,be2a, WA2,BA2);
    k_layer_mfma<<<grid128,blk,0,stream>>>(hh, WA2,BA2, WT2,b2b, ZT, S4B);
    k_fold_affine<<<1,256,0,stream>>>(S4B, g2b, be2b, SC4, TC4);
    k_consume_out<<<grid512,blk,0,stream>>>(ZT, SC4,TC4, W2c,b2c, (float*)d_out);
  } else {
    hipMemsetAsync(M1, 0, (65+512+65+512)*sizeof(float), stream);
    k_attn_in<<<grid256,blk,0,stream>>>(x, Wq1,Wk1,Wv1,Wo1, h, P1);
    k_fold10_part<<<1,576,0,stream>>>(P1, 512, W1a,b1a,g1a,be1a, WA1,BA1);
    k_mid<<<grid256,blk,0,stream>>>(h, WA1,BA1, W1b,b1b, S2);
    k_fold_big<<<1,256,0,stream>>>(S2, W1b,b1b,g1b,be1b, WB1,BB1);
    k_mid2<<<grid256,blk,0,stream>>>(h, WA1,BA1, WB1,BB1, W1c,b1c,
                                     Wq2,Wk2,Wv2,Wo2, hh, M3);
    k_fold10_atomic<<<1,128,0,stream>>>(M3, W2a,b2a,g2a,be2a, WA2,BA2);
    k_mid<<<grid256,blk,0,stream>>>(hh, WA2,BA2, W2b,b2b, S4);
    k_fold_big<<<1,256,0,stream>>>(S4, W2b,b2b,g2b,be2b, WB2,BB2);
    k_out<<<grid256,blk,0,stream>>>(hh, WA2,BA2, WB2,BB2, W2c,b2c, (float*)d_out);
  }
}

// Round 16
// 206.962 us; speedup vs baseline: 1.1294x; 1.1294x over previous
//
#include <hip/hip_runtime.h>
#include <hip/hip_bf16.h>

#define EPS 1e-5f
constexpr int BN = 131072;
constexpr int NBKT = 32;
constexpr int NTILE = BN/64;           // 2048 tiles
constexpr int TILE_ELEMS = 256*64;     // 16384 bf16 per tile (32 KB)

typedef __attribute__((ext_vector_type(8))) short bf16x8;
typedef __attribute__((ext_vector_type(4))) float f32x4;

// ---- workspace layout (float offsets) ----
constexpr size_t OFF_H   = 0;
constexpr size_t OFF_HH  = OFF_H  + (size_t)BN*10;
constexpr size_t OFF_M1  = OFF_HH + (size_t)BN*10;
constexpr size_t OFF_S2  = OFF_M1 + 65;
constexpr size_t OFF_M3  = OFF_S2 + 512;
constexpr size_t OFF_S4  = OFF_M3 + 65;
constexpr size_t OFF_WA1 = OFF_S4 + 512;
constexpr size_t OFF_BA1 = OFF_WA1 + 1280;
constexpr size_t OFF_WA2 = OFF_BA1 + 128;
constexpr size_t OFF_BA2 = OFF_WA2 + 1280;
constexpr size_t OFF_SC2 = OFF_BA2 + 128;
constexpr size_t OFF_TC2 = OFF_SC2 + 256;
constexpr size_t OFF_SC4 = OFF_TC2 + 256;
constexpr size_t OFF_TC4 = OFF_SC4 + 256;
constexpr size_t OFF_WB1 = OFF_TC4 + 256;
constexpr size_t OFF_BB1 = OFF_WB1 + 32768;
constexpr size_t OFF_WB2 = OFF_BB1 + 256;
constexpr size_t OFF_BB2 = OFF_WB2 + 32768;
constexpr size_t OFF_P1  = OFF_BB2 + 256;             // 1024x65 moment partials
constexpr size_t OFF_P3  = OFF_P1 + 1024*65;
constexpr size_t OFF_S2B = OFF_P3 + 1024*65;          // NBKT x 512 bucket stats
constexpr size_t OFF_S4B = OFF_S2B + (size_t)NBKT*512;
constexpr size_t OFF_WT1 = OFF_S4B + (size_t)NBKT*512;
constexpr size_t OFF_WT2 = OFF_WT1 + 16384;
constexpr size_t OFF_END = OFF_WT2 + 16384;
constexpr size_t OFF_Z_BYTES = ((OFF_END*4 + 255) & ~(size_t)255); // tiled z
constexpr size_t WS_NEED = OFF_Z_BYTES + (size_t)NTILE*TILE_ELEMS*2;

__device__ __forceinline__ float wsum(float v){
  v += __shfl_down(v, 32);
  v += __shfl_down(v, 16);
  v += __shfl_down(v, 8);
  v += __shfl_down(v, 4);
  v += __shfl_down(v, 2);
  v += __shfl_down(v, 1);
  return v;
}

__device__ __forceinline__ unsigned pk_bf16(float a, float b){
  union { __hip_bfloat16 h[2]; unsigned u; } cv;
  cv.h[0] = __float2bfloat16(a);
  cv.h[1] = __float2bfloat16(b);
  return cv.u;
}

__device__ __forceinline__ unsigned short bf16_1(float a){
  union { __hip_bfloat16 h; unsigned short u; } cv;
  cv.h = __float2bfloat16(a);
  return cv.u;
}

__device__ __forceinline__ float bf16_to_f(unsigned short u){
  return __uint_as_float(((unsigned)u) << 16);
}

// attention on a 10-vector: softmax over q (axis=1!) per column k
__device__ __forceinline__ void attn10(const float* xr, float cqk, float cvo, float* y){
  #pragma unroll
  for (int q=0;q<10;q++) y[q] = 0.f;
  #pragma unroll
  for (int k=0;k<10;k++){
    float t = cqk * xr[k];
    float m = t*xr[0];
    #pragma unroll
    for (int q=1;q<10;q++) m = fmaxf(m, t*xr[q]);
    float ex[10]; float s = 0.f;
    #pragma unroll
    for (int q=0;q<10;q++){ ex[q] = __expf(t*xr[q]-m); s += ex[q]; }
    float f = xr[k]/s;
    #pragma unroll
    for (int q=0;q<10;q++) y[q] += ex[q]*f;
  }
  #pragma unroll
  for (int q=0;q<10;q++) y[q] *= cvo;
}

// block-level moment reduction (256 rows, 4 waves)
__device__ __forceinline__ void moments_block(const float* y, float (*red)[65],
                                              float* Pb, int t){
  int lane = t & 63, w = t >> 6;
  #pragma unroll
  for (int i=0;i<10;i++){
    float v = wsum(y[i]);
    if (lane==0) red[w][i] = v;
  }
  #pragma unroll
  for (int i=0;i<10;i++){
    #pragma unroll
    for (int j=i;j<10;j++){
      float v = wsum(y[i]*y[j]);
      if (lane==0) red[w][10 + 10*i - i*(i-1)/2 + (j-i)] = v;
    }
  }
  __syncthreads();
  if (t < 65)
    Pb[(size_t)blockIdx.x*65 + t] = red[0][t]+red[1][t]+red[2][t]+red[3][t];
}

// legacy atomic moments (fallback path only)
__device__ __forceinline__ void moments10(const float* y, float* M, int lane){
  #pragma unroll
  for (int i=0;i<10;i++){
    float s = wsum(y[i]);
    if (lane==0) atomicAdd(&M[i], s);
  }
  #pragma unroll
  for (int i=0;i<10;i++){
    #pragma unroll
    for (int j=i;j<10;j++){
      int id = 10*i - i*(i-1)/2 + (j-i);
      float s = wsum(y[i]*y[j]);
      if (lane==0) atomicAdd(&M[10+id], s);
    }
  }
}

// K1: x -> attn1 -> h  (staged loads/stores + per-block moment partials)
__global__ __launch_bounds__(256) void k_attn_in(
    const float* __restrict__ x,
    const float* __restrict__ Wq, const float* __restrict__ Wk,
    const float* __restrict__ Wv, const float* __restrict__ Wo,
    float* __restrict__ h, float* __restrict__ Pb){
  __shared__ float xs[256][11];
  __shared__ float red[4][65];
  int t = threadIdx.x;
  size_t base = (size_t)blockIdx.x*2560;
  for (int idx=t; idx<2560; idx+=256) xs[idx/10][idx%10] = x[base+idx];
  float cqk=0.f, cvo=0.f;
  #pragma unroll
  for (int d=0;d<16;d++){ cqk += Wq[d]*Wk[d]; cvo += Wv[d]*Wo[d]; }
  cqk *= 0.25f;
  __syncthreads();
  float xr[10];
  #pragma unroll
  for (int q=0;q<10;q++) xr[q] = xs[t][q];
  float y[10];
  attn10(xr, cqk, cvo, y);
  #pragma unroll
  for (int q=0;q<10;q++) xs[t][q] = y[q];
  moments_block(y, red, Pb, t);   // contains a __syncthreads()
  for (int idx=t; idx<2560; idx+=256) h[base+idx] = xs[idx/10][idx%10];
}

// fold BN over (10,128) from npart moment-partials -> WT (128,10), bo (128)
// launch with 576 threads
__global__ void k_fold10_part(const float* __restrict__ Pb, int npart,
                              const float* __restrict__ W,
                              const float* __restrict__ bv, const float* __restrict__ g,
                              const float* __restrict__ be,
                              float* __restrict__ WT, float* __restrict__ bo){
  __shared__ float part[65][8];
  __shared__ float sM[65];
  int t = threadIdx.x;
  if (t < 520){
    int c = t>>3, k = t&7;
    int n = npart>>3;
    float acc = 0.f;
    #pragma unroll 4
    for (int i=0;i<n;i++) acc += Pb[(size_t)(k*n+i)*65 + c];
    part[c][k] = acc;
  }
  __syncthreads();
  if (t < 65){
    float a = 0.f;
    #pragma unroll
    for (int k=0;k<8;k++) a += part[t][k];
    sM[t] = a;
  }
  __syncthreads();
  int j = t;
  if (j >= 128) return;
  const float invB = 1.f/(float)BN;
  float Eh[10];
  #pragma unroll
  for (int i=0;i<10;i++) Eh[i] = sM[i]*invB;
  float wj[10];
  #pragma unroll
  for (int i=0;i<10;i++) wj[i] = W[i*128+j];
  float mu = bv[j];
  #pragma unroll
  for (int i=0;i<10;i++) mu += Eh[i]*wj[i];
  float var = 0.f;
  #pragma unroll
  for (int i=0;i<10;i++){
    #pragma unroll
    for (int l=0;l<10;l++){
      int a = i<l ? i : l, c = i<l ? l : i;
      int id = 10*a - a*(a-1)/2 + (c-a);
      float cov = sM[10+id]*invB - Eh[i]*Eh[l];
      var += wj[i]*wj[l]*cov;
    }
  }
  float s = g[j]*rsqrtf(var + EPS);
  #pragma unroll
  for (int i=0;i<10;i++) WT[j*10+i] = wj[i]*s;
  bo[j] = (bv[j]-mu)*s + be[j];
}

// legacy atomic-M fold (fallback path only)
__global__ void k_fold10_atomic(const float* __restrict__ M,
                                const float* __restrict__ W,
                                const float* __restrict__ bv, const float* __restrict__ g,
                                const float* __restrict__ be,
                                float* __restrict__ WT, float* __restrict__ bo){
  int j = threadIdx.x;
  if (j >= 128) return;
  const float invB = 1.f/(float)BN;
  float Eh[10];
  #pragma unroll
  for (int i=0;i<10;i++) Eh[i] = M[i]*invB;
  float wj[10];
  #pragma unroll
  for (int i=0;i<10;i++) wj[i] = W[i*128+j];
  float mu = bv[j];
  #pragma unroll
  for (int i=0;i<10;i++) mu += Eh[i]*wj[i];
  float var = 0.f;
  #pragma unroll
  for (int i=0;i<10;i++){
    #pragma unroll
    for (int l=0;l<10;l++){
      int a = i<l ? i : l, c = i<l ? l : i;
      int id = 10*a - a*(a-1)/2 + (c-a);
      float cov = M[10+id]*invB - Eh[i]*Eh[l];
      var += wj[i]*wj[l]*cov;
    }
  }
  float s = g[j]*rsqrtf(var + EPS);
  #pragma unroll
  for (int i=0;i<10;i++) WT[j*10+i] = wj[i]*s;
  bo[j] = (bv[j]-mu)*s + be[j];
}

// BN fold as per-column affine from NBKT bucket stats (z includes bias)
__global__ void k_fold_affine(const float* __restrict__ stats,
                              const float* __restrict__ g,
                              const float* __restrict__ be,
                              float* __restrict__ s, float* __restrict__ tt){
  int j = threadIdx.x;
  if (j >= 256) return;
  float su = 0.f, sq = 0.f;
  #pragma unroll 4
  for (int k=0;k<NBKT;k++){
    su += stats[k*512 + j];
    sq += stats[k*512 + 256 + j];
  }
  const float invB = 1.f/(float)BN;
  float mu  = su*invB;
  float var = sq*invB - mu*mu;
  float sc = g[j]*rsqrtf(var + EPS);
  s[j]  = sc;
  tt[j] = be[j] - mu*sc;
}

// transpose+convert both W (128,256) f32 -> WT (256,128) bf16 ; grid 256
__global__ __launch_bounds__(256) void k_prep_wt2(
    const float* __restrict__ W1, const float* __restrict__ W2,
    unsigned short* __restrict__ WT1, unsigned short* __restrict__ WT2){
  int g = blockIdx.x;
  const float* W = (g < 128) ? W1 : W2;
  unsigned short* WT = (g < 128) ? WT1 : WT2;
  int idx = (g & 127)*256 + threadIdx.x;
  int c = idx >> 7, k = idx & 127;
  WT[idx] = bf16_1(W[k*256 + c]);
}

// ===================== 2-slab pipelined producer =====================
// grid BN/128; block handles slabs 2*bid, 2*bid+1 (64 rows each).
// tile s: 32 KB contiguous at (2*bid+s)*TILE_ELEMS, layout [256 cols][64 rows]
__global__ __launch_bounds__(256) void k_layer_mfma(
    const float* __restrict__ h,            // (B,10)
    const float* __restrict__ WaT,          // (128,10) folded
    const float* __restrict__ ba,           // (128)
    const unsigned short* __restrict__ WT,  // (256,128) bf16
    const float* __restrict__ bb,           // (256)
    unsigned short* __restrict__ zt,        // tiled z out
    float* __restrict__ stats)              // NBKT x 512: sum | sumsq
{
  __shared__ unsigned short h1s[2][64*128]; // 32 KB double buffer
  __shared__ float hs[128][11];             // 5.6 KB
  __shared__ float sWaT[1280];              // 5 KB
  int t = threadIdx.x;
  int lane = t & 63, w = t >> 6;
  int ci = lane & 15, g = lane >> 4;
  size_t row0 = (size_t)blockIdx.x * 128;

  // B fragments from L2 (once for both slabs)
  bf16x8 bfr[4][4];
  #pragma unroll
  for (int nt=0; nt<4; nt++)
    #pragma unroll
    for (int kt=0; kt<4; kt++){
      union { uint4 u; bf16x8 v; } cv;
      cv.u = *(const uint4*)(WT + (size_t)(w*64 + nt*16 + ci)*128 + kt*32 + g*8);
      bfr[nt][kt] = cv.v;
    }

  for (int idx = t; idx < 1280; idx += 256) hs[idx/10][idx%10] = h[row0*10 + idx];
  for (int idx = t; idx < 1280; idx += 256) sWaT[idx] = WaT[idx];
  __syncthreads();

  float bbv[4];
  #pragma unroll
  for (int nt=0;nt<4;nt++) bbv[nt] = bb[w*64 + nt*16 + ci];
  float cs[4] = {0,0,0,0}, cq[4] = {0,0,0,0};

  // ---- phase1 slab 0 ----
  {
    int r = lane;
    int i0 = w * 32;
    float hr[10];
    #pragma unroll
    for (int l=0;l<10;l++) hr[l] = hs[r][l];
    #pragma unroll
    for (int j=0;j<4;j++){
      unsigned pk[4];
      #pragma unroll
      for (int q=0;q<4;q++){
        int i = i0 + j*8 + q*2;
        float v0 = ba[i], v1 = ba[i+1];
        #pragma unroll
        for (int l=0;l<10;l++){
          v0 = fmaf(hr[l], sWaT[i*10+l],     v0);
          v1 = fmaf(hr[l], sWaT[(i+1)*10+l], v1);
        }
        pk[q] = pk_bf16(fmaxf(v0,0.f), fmaxf(v1,0.f));
      }
      int byte = r*256 + (((i0 + j*8)*2) ^ ((r&7)<<4));
      *(uint4*)((char*)h1s[0] + byte) = make_uint4(pk[0],pk[1],pk[2],pk[3]);
    }
  }
  __syncthreads();

  // ---- MFMA slab 0 ----
  f32x4 acc[4][4];
  #pragma unroll
  for (int mt=0;mt<4;mt++)
    #pragma unroll
    for (int nt=0;nt<4;nt++)
      acc[mt][nt] = (f32x4){0.f,0.f,0.f,0.f};
  #pragma unroll
  for (int mt=0; mt<4; mt++){
    int r = mt*16 + ci;
    bf16x8 af[4];
    #pragma unroll
    for (int kt=0; kt<4; kt++){
      int byte = r*256 + ((kt*64 + g*16) ^ ((r&7)<<4));
      af[kt] = *(const bf16x8*)((const char*)h1s[0] + byte);
    }
    #pragma unroll
    for (int nt=0; nt<4; nt++)
      #pragma unroll
      for (int kt=0; kt<4; kt++)
        acc[mt][nt] = __builtin_amdgcn_mfma_f32_16x16x32_bf16(
            af[kt], bfr[nt][kt], acc[mt][nt], 0, 0, 0);
  }

  // ---- epilogue slab 0: issue stores, accumulate stats ----
  {
    size_t tbase = ((size_t)blockIdx.x*2 + 0) * TILE_ELEMS;
    #pragma unroll
    for (int nt=0; nt<4; nt++){
      int c = w*64 + nt*16 + ci;
      #pragma unroll
      for (int mt=0; mt<4; mt++){
        float z0 = acc[mt][nt][0] + bbv[nt];
        float z1 = acc[mt][nt][1] + bbv[nt];
        float z2 = acc[mt][nt][2] + bbv[nt];
        float z3 = acc[mt][nt][3] + bbv[nt];
        cs[nt] += z0+z1+z2+z3;
        cq[nt] += z0*z0+z1*z1+z2*z2+z3*z3;
        *(uint2*)(zt + tbase + c*64 + mt*16 + g*4) =
            make_uint2(pk_bf16(z0,z1), pk_bf16(z2,z3));
      }
    }
  }

  // ---- phase1 slab 1 (hides slab-0 store latency) ----
  {
    int r = lane;
    int i0 = w * 32;
    float hr[10];
    #pragma unroll
    for (int l=0;l<10;l++) hr[l] = hs[64 + r][l];
    #pragma unroll
    for (int j=0;j<4;j++){
      unsigned pk[4];
      #pragma unroll
      for (int q=0;q<4;q++){
        int i = i0 + j*8 + q*2;
        float v0 = ba[i], v1 = ba[i+1];
        #pragma unroll
        for (int l=0;l<10;l++){
          v0 = fmaf(hr[l], sWaT[i*10+l],     v0);
          v1 = fmaf(hr[l], sWaT[(i+1)*10+l], v1);
        }
        pk[q] = pk_bf16(fmaxf(v0,0.f), fmaxf(v1,0.f));
      }
      int byte = r*256 + (((i0 + j*8)*2) ^ ((r&7)<<4));
      *(uint4*)((char*)h1s[1] + byte) = make_uint4(pk[0],pk[1],pk[2],pk[3]);
    }
  }
  __syncthreads();

  // ---- MFMA slab 1 ----
  #pragma unroll
  for (int mt=0;mt<4;mt++)
    #pragma unroll
    for (int nt=0;nt<4;nt++)
      acc[mt][nt] = (f32x4){0.f,0.f,0.f,0.f};
  #pragma unroll
  for (int mt=0; mt<4; mt++){
    int r = mt*16 + ci;
    bf16x8 af[4];
    #pragma unroll
    for (int kt=0; kt<4; kt++){
      int byte = r*256 + ((kt*64 + g*16) ^ ((r&7)<<4));
      af[kt] = *(const bf16x8*)((const char*)h1s[1] + byte);
    }
    #pragma unroll
    for (int nt=0; nt<4; nt++)
      #pragma unroll
      for (int kt=0; kt<4; kt++)
        acc[mt][nt] = __builtin_amdgcn_mfma_f32_16x16x32_bf16(
            af[kt], bfr[nt][kt], acc[mt][nt], 0, 0, 0);
  }

  // ---- epilogue slab 1 ----
  {
    size_t tbase = ((size_t)blockIdx.x*2 + 1) * TILE_ELEMS;
    #pragma unroll
    for (int nt=0; nt<4; nt++){
      int c = w*64 + nt*16 + ci;
      #pragma unroll
      for (int mt=0; mt<4; mt++){
        float z0 = acc[mt][nt][0] + bbv[nt];
        float z1 = acc[mt][nt][1] + bbv[nt];
        float z2 = acc[mt][nt][2] + bbv[nt];
        float z3 = acc[mt][nt][3] + bbv[nt];
        cs[nt] += z0+z1+z2+z3;
        cq[nt] += z0*z0+z1*z1+z2*z2+z3*z3;
        *(uint2*)(zt + tbase + c*64 + mt*16 + g*4) =
            make_uint2(pk_bf16(z0,z1), pk_bf16(z2,z3));
      }
    }
  }

  // ---- stats: one reduce+atomic set per block (covers 128 rows) ----
  #pragma unroll
  for (int nt=0; nt<4; nt++){
    float s1 = cs[nt], s2 = cq[nt];
    s1 += __shfl_down(s1, 32); s1 += __shfl_down(s1, 16);
    s2 += __shfl_down(s2, 32); s2 += __shfl_down(s2, 16);
    if (lane < 16){
      int bkt = blockIdx.x & (NBKT-1);
      int c = w*64 + nt*16 + ci;
      atomicAdd(&stats[bkt*512 + c],       s1);
      atomicAdd(&stats[bkt*512 + 256 + c], s2);
    }
  }
}

// ===================== consume tiled z: double-buffered 32-col chunks ==========
// block handles 256 rows = tiles bid*4..bid*4+3
__global__ __launch_bounds__(256) void k_consume_mid(
    const unsigned short* __restrict__ zt,
    const float* __restrict__ s_g, const float* __restrict__ t_g,
    const float* __restrict__ Wc,  const float* __restrict__ bc,
    const float* __restrict__ Wq, const float* __restrict__ Wk,
    const float* __restrict__ Wv, const float* __restrict__ Wo,
    float* __restrict__ hh, float* __restrict__ Pb){
  __shared__ __align__(16) unsigned short zs[2][32*256];  // 2 x 16 KB chunk tiles
  __shared__ __align__(16) float sWc[256*12];             // 12 KB padded
  __shared__ float ss[256], st[256];
  __shared__ float red[4][65];
  int t = threadIdx.x;
  for (int idx=t; idx<2560; idx+=256) sWc[(idx/10)*12 + (idx%10)] = Wc[idx];
  ss[t] = s_g[t]; st[t] = t_g[t];
  size_t b0 = (size_t)blockIdx.x*256;

  float z3[10];
  #pragma unroll
  for (int l=0;l<10;l++) z3[l] = bc[l];

  int q = t >> 6, l = t & 63;    // tile q, lane l: 32 contiguous u16 per thread
  size_t src_base = ((size_t)blockIdx.x*4 + q)*TILE_ELEMS + l*32;
  int dst_off = (l>>1)*256 + q*64 + (l&1)*32;   // zs[col][tile-row]
  uint4 r0, r1, r2, r3;
  {
    const uint4* src = (const uint4*)(zt + src_base);
    r0 = src[0]; r1 = src[1]; r2 = src[2]; r3 = src[3];
    uint4* dst = (uint4*)&zs[0][dst_off];
    dst[0] = r0; dst[1] = r1; dst[2] = r2; dst[3] = r3;
  }
  for (int cc=0; cc<8; cc++){
    __syncthreads();    // buf[cc&1] visible (also covers sWc/ss on first iter)
    if (cc < 7){
      const uint4* src = (const uint4*)(zt + src_base + (size_t)(cc+1)*2048);
      r0 = src[0]; r1 = src[1]; r2 = src[2]; r3 = src[3];
    }
    const unsigned short* zb = zs[cc&1];
    #pragma unroll 4
    for (int cl=0; cl<32; cl++){
      int c = cc*32 + cl;
      float f = bf16_to_f(zb[cl*256 + t]);
      float h2 = fmaxf(fmaf(ss[c], f, st[c]), 0.f);
      const float4* wr = (const float4*)&sWc[c*12];
      float4 w0 = wr[0];
      float4 w1 = wr[1];
      float2 w2 = *(const float2*)&sWc[c*12 + 8];
      z3[0] = fmaf(h2, w0.x, z3[0]); z3[1] = fmaf(h2, w0.y, z3[1]);
      z3[2] = fmaf(h2, w0.z, z3[2]); z3[3] = fmaf(h2, w0.w, z3[3]);
      z3[4] = fmaf(h2, w1.x, z3[4]); z3[5] = fmaf(h2, w1.y, z3[5]);
      z3[6] = fmaf(h2, w1.z, z3[6]); z3[7] = fmaf(h2, w1.w, z3[7]);
      z3[8] = fmaf(h2, w2.x, z3[8]); z3[9] = fmaf(h2, w2.y, z3[9]);
    }
    if (cc < 7){
      uint4* dst = (uint4*)&zs[(cc+1)&1][dst_off];
      dst[0] = r0; dst[1] = r1; dst[2] = r2; dst[3] = r3;
    }
  }

  float cqk=0.f, cvo=0.f;
  #pragma unroll
  for (int d=0;d<16;d++){ cqk += Wq[d]*Wk[d]; cvo += Wv[d]*Wo[d]; }
  cqk *= 0.25f;
  float y[10];
  attn10(z3, cqk, cvo, y);
  __syncthreads();                 // all compute done; zs[0] reusable as staging
  float* hhs = (float*)zs[0];
  #pragma unroll
  for (int qq=0;qq<10;qq++) hhs[t*10+qq] = y[qq];
  moments_block(y, red, Pb, t);    // contains a __syncthreads()
  for (int idx=t; idx<2560; idx+=256)
    hh[b0*10 + idx] = hhs[idx];
}

// consume tiled z: h5 = relu(s*z+t) -> out = h5 @ Wc(256,2) + bc
__global__ __launch_bounds__(256) void k_consume_out(
    const unsigned short* __restrict__ zt,
    const float* __restrict__ s_g, const float* __restrict__ t_g,
    const float* __restrict__ Wc,  const float* __restrict__ bc,
    float* __restrict__ out){
  __shared__ __align__(16) unsigned short zs[2][32*256];
  __shared__ __align__(8) float sWo[512];   // [c][2]
  __shared__ float ss[256], st[256];
  int t = threadIdx.x;
  sWo[t] = Wc[t]; sWo[256+t] = Wc[256+t];
  ss[t] = s_g[t]; st[t] = t_g[t];
  size_t b0 = (size_t)blockIdx.x*256;
  float o0 = bc[0], o1 = bc[1];
  int q = t >> 6, l = t & 63;
  size_t src_base = ((size_t)blockIdx.x*4 + q)*TILE_ELEMS + l*32;
  int dst_off = (l>>1)*256 + q*64 + (l&1)*32;
  uint4 r0, r1, r2, r3;
  {
    const uint4* src = (const uint4*)(zt + src_base);
    r0 = src[0]; r1 = src[1]; r2 = src[2]; r3 = src[3];
    uint4* dst = (uint4*)&zs[0][dst_off];
    dst[0] = r0; dst[1] = r1; dst[2] = r2; dst[3] = r3;
  }
  for (int cc=0; cc<8; cc++){
    __syncthreads();
    if (cc < 7){
      const uint4* src = (const uint4*)(zt + src_base + (size_t)(cc+1)*2048);
      r0 = src[0]; r1 = src[1]; r2 = src[2]; r3 = src[3];
    }
    const unsigned short* zb = zs[cc&1];
    #pragma unroll 8
    for (int cl=0; cl<32; cl++){
      int c = cc*32 + cl;
      float f = bf16_to_f(zb[cl*256 + t]);
      float h5 = fmaxf(fmaf(ss[c], f, st[c]), 0.f);
      float2 wv = *(const float2*)&sWo[c*2];
      o0 = fmaf(h5, wv.x, o0);
      o1 = fmaf(h5, wv.y, o1);
    }
    if (cc < 7){
      uint4* dst = (uint4*)&zs[(cc+1)&1][dst_off];
      dst[0] = r0; dst[1] = r1; dst[2] = r2; dst[3] = r3;
    }
  }
  *(float2*)(out + (b0 + t)*2) = make_float2(o0, o1);
}

// ===================== slow fallback path (round-0 style) =====================
__global__ void k_fold_big(const float* __restrict__ stats,
                           const float* __restrict__ W,
                           const float* __restrict__ bv, const float* __restrict__ g,
                           const float* __restrict__ be,
                           float* __restrict__ Wf, float* __restrict__ bf){
  int j = blockIdx.x*256 + threadIdx.x;
  if (j >= 256) return;
  const float invB = 1.f/(float)BN;
  float mu  = stats[j]*invB;
  float var = stats[256+j]*invB - mu*mu;
  float s = g[j]*rsqrtf(var + EPS);
  bf[j] = (bv[j]-mu)*s + be[j];
  for (int i=0;i<128;i++) Wf[i*256+j] = W[i*256+j]*s;
}

__global__ __launch_bounds__(256) void k_mid(
    const float* __restrict__ h,
    const float* __restrict__ WaT, const float* __restrict__ ba,
    const float* __restrict__ Wb,  const float* __restrict__ bb,
    float* __restrict__ stats){
  int b = blockIdx.x*256 + threadIdx.x;
  if (b >= BN) return;
  float hr[10];
  #pragma unroll
  for (int l=0;l<10;l++) hr[l] = h[(size_t)b*10+l];
  int lane = threadIdx.x & 63;
  for (int jc=0;jc<4;jc++){
    float acc[64];
    #pragma unroll
    for (int j=0;j<64;j++) acc[j] = bb[jc*64+j];
    for (int i=0;i<128;i++){
      float h1 = ba[i];
      #pragma unroll
      for (int l=0;l<10;l++) h1 += hr[l]*WaT[i*10+l];
      h1 = fmaxf(h1, 0.f);
      const float* __restrict__ w = &Wb[i*256 + jc*64];
      #pragma unroll
      for (int j=0;j<64;j++) acc[j] += h1*w[j];
    }
    #pragma unroll
    for (int j=0;j<64;j++){
      float s1 = wsum(acc[j]);
      float s2 = wsum(acc[j]*acc[j]);
      if (lane==0){
        atomicAdd(&stats[jc*64+j], s1);
        atomicAdd(&stats[256+jc*64+j], s2);
      }
    }
  }
}

__global__ __launch_bounds__(256) void k_mid2(
    const float* __restrict__ h,
    const float* __restrict__ WaT, const float* __restrict__ ba,
    const float* __restrict__ Wbf, const float* __restrict__ bbf,
    const float* __restrict__ Wc,  const float* __restrict__ bc,
    const float* __restrict__ Wq, const float* __restrict__ Wk,
    const float* __restrict__ Wv, const float* __restrict__ Wo,
    float* __restrict__ hh, float* __restrict__ M){
  int b = blockIdx.x*256 + threadIdx.x;
  if (b >= BN) return;
  float hr[10];
  #pragma unroll
  for (int l=0;l<10;l++) hr[l] = h[(size_t)b*10+l];
  float z3[10];
  #pragma unroll
  for (int l=0;l<10;l++) z3[l] = bc[l];
  for (int jc=0;jc<4;jc++){
    float acc[64];
    #pragma unroll
    for (int j=0;j<64;j++) acc[j] = bbf[jc*64+j];
    for (int i=0;i<128;i++){
      float h1 = ba[i];
      #pragma unroll
      for (int l=0;l<10;l++) h1 += hr[l]*WaT[i*10+l];
      h1 = fmaxf(h1, 0.f);
      const float* __restrict__ w = &Wbf[i*256 + jc*64];
      #pragma unroll
      for (int j=0;j<64;j++) acc[j] += h1*w[j];
    }
    #pragma unroll
    for (int j=0;j<64;j++){
      float h2 = fmaxf(acc[j], 0.f);
      const float* __restrict__ wc = &Wc[(jc*64+j)*10];
      #pragma unroll
      for (int l=0;l<10;l++) z3[l] += h2*wc[l];
    }
  }
  float cqk=0.f, cvo=0.f;
  #pragma unroll
  for (int d=0;d<16;d++){ cqk += Wq[d]*Wk[d]; cvo += Wv[d]*Wo[d]; }
  cqk *= 0.25f;
  float y[10];
  attn10(z3, cqk, cvo, y);
  #pragma unroll
  for (int q=0;q<10;q++) hh[(size_t)b*10+q] = y[q];
  moments10(y, M, threadIdx.x & 63);
}

__global__ __launch_bounds__(256) void k_out(
    const float* __restrict__ h,
    const float* __restrict__ WaT, const float* __restrict__ ba,
    const float* __restrict__ Wbf, const float* __restrict__ bbf,
    const float* __restrict__ Wc,  const float* __restrict__ bc,
    float* __restrict__ out){
  int b = blockIdx.x*256 + threadIdx.x;
  if (b >= BN) return;
  float hr[10];
  #pragma unroll
  for (int l=0;l<10;l++) hr[l] = h[(size_t)b*10+l];
  float o0 = bc[0], o1 = bc[1];
  for (int jc=0;jc<4;jc++){
    float acc[64];
    #pragma unroll
    for (int j=0;j<64;j++) acc[j] = bbf[jc*64+j];
    for (int i=0;i<128;i++){
      float h4 = ba[i];
      #pragma unroll
      for (int l=0;l<10;l++) h4 += hr[l]*WaT[i*10+l];
      h4 = fmaxf(h4, 0.f);
      const float* __restrict__ w = &Wbf[i*256 + jc*64];
      #pragma unroll
      for (int j=0;j<64;j++) acc[j] += h4*w[j];
    }
    #pragma unroll
    for (int j=0;j<64;j++){
      float h5 = fmaxf(acc[j], 0.f);
      o0 += h5*Wc[(jc*64+j)*2];
      o1 += h5*Wc[(jc*64+j)*2+1];
    }
  }
  out[(size_t)b*2]   = o0;
  out[(size_t)b*2+1] = o1;
}

extern "C" void kernel_launch(void* const* d_in, const int* in_sizes, int n_in,
                              void* d_out, int out_size, void* d_ws, size_t ws_size,
                              hipStream_t stream){
  const float* x   = (const float*)d_in[0];
  const float* Wq1 = (const float*)d_in[1];
  const float* Wk1 = (const float*)d_in[2];
  const float* Wv1 = (const float*)d_in[3];
  const float* Wo1 = (const float*)d_in[4];
  const float* Wq2 = (const float*)d_in[5];
  const float* Wk2 = (const float*)d_in[6];
  const float* Wv2 = (const float*)d_in[7];
  const float* Wo2 = (const float*)d_in[8];
  const float* W1a = (const float*)d_in[9];  const float* b1a = (const float*)d_in[10];
  const float* g1a = (const float*)d_in[11]; const float* be1a= (const float*)d_in[12];
  const float* W1b = (const float*)d_in[13]; const float* b1b = (const float*)d_in[14];
  const float* g1b = (const float*)d_in[15]; const float* be1b= (const float*)d_in[16];
  const float* W1c = (const float*)d_in[17]; const float* b1c = (const float*)d_in[18];
  const float* W2a = (const float*)d_in[19]; const float* b2a = (const float*)d_in[20];
  const float* g2a = (const float*)d_in[21]; const float* be2a= (const float*)d_in[22];
  const float* W2b = (const float*)d_in[23]; const float* b2b = (const float*)d_in[24];
  const float* g2b = (const float*)d_in[25]; const float* be2b= (const float*)d_in[26];
  const float* W2c = (const float*)d_in[27]; const float* b2c = (const float*)d_in[28];

  float* f   = (float*)d_ws;
  float* h   = f + OFF_H;
  float* hh  = f + OFF_HH;
  float* M1  = f + OFF_M1;
  float* S2  = f + OFF_S2;
  float* M3  = f + OFF_M3;
  float* S4  = f + OFF_S4;
  float* WA1 = f + OFF_WA1; float* BA1 = f + OFF_BA1;
  float* WA2 = f + OFF_WA2; float* BA2 = f + OFF_BA2;
  float* SC2 = f + OFF_SC2; float* TC2 = f + OFF_TC2;
  float* SC4 = f + OFF_SC4; float* TC4 = f + OFF_TC4;
  float* WB1 = f + OFF_WB1; float* BB1 = f + OFF_BB1;
  float* WB2 = f + OFF_WB2; float* BB2 = f + OFF_BB2;
  float* P1  = f + OFF_P1;  float* P3  = f + OFF_P3;
  float* S2B = f + OFF_S2B; float* S4B = f + OFF_S4B;
  unsigned short* WT1 = (unsigned short*)(f + OFF_WT1);
  unsigned short* WT2 = (unsigned short*)(f + OFF_WT2);
  unsigned short* ZT = (unsigned short*)((char*)d_ws + OFF_Z_BYTES);

  dim3 blk(256);
  dim3 grid256(BN/256);   // 512
  dim3 grid128(BN/128);   // 1024

  if (ws_size >= WS_NEED){
    hipMemsetAsync(S2B, 0, (size_t)2*NBKT*512*sizeof(float), stream);
    k_prep_wt2<<<256,blk,0,stream>>>(W1b, W2b, WT1, WT2);
    k_attn_in<<<grid256,blk,0,stream>>>(x, Wq1,Wk1,Wv1,Wo1, h, P1);
    k_fold10_part<<<1,576,0,stream>>>(P1, 512, W1a,b1a,g1a,be1a, WA1,BA1);
    k_layer_mfma<<<grid128,blk,0,stream>>>(h, WA1,BA1, WT1,b1b, ZT, S2B);
    k_fold_affine<<<1,256,0,stream>>>(S2B, g1b, be1b, SC2, TC2);
    k_consume_mid<<<grid256,blk,0,stream>>>(ZT, SC2,TC2, W1c,b1c,
                                            Wq2,Wk2,Wv2,Wo2, hh, P3);
    k_fold10_part<<<1,576,0,stream>>>(P3, 512, W2a,b2a,g2a,be2a, WA2,BA2);
    k_layer_mfma<<<grid128,blk,0,stream>>>(hh, WA2,BA2, WT2,b2b, ZT, S4B);
    k_fold_affine<<<1,256,0,stream>>>(S4B, g2b, be2b, SC4, TC4);
    k_consume_out<<<grid256,blk,0,stream>>>(ZT, SC4,TC4, W2c,b2c, (float*)d_out);
  } else {
    hipMemsetAsync(M1, 0, (65+512+65+512)*sizeof(float), stream);
    k_attn_in<<<grid256,blk,0,stream>>>(x, Wq1,Wk1,Wv1,Wo1, h, P1);
    k_fold10_part<<<1,576,0,stream>>>(P1, 512, W1a,b1a,g1a,be1a, WA1,BA1);
    k_mid<<<grid256,blk,0,stream>>>(h, WA1,BA1, W1b,b1b, S2);
    k_fold_big<<<1,256,0,stream>>>(S2, W1b,b1b,g1b,be1b, WB1,BB1);
    k_mid2<<<grid256,blk,0,stream>>>(h, WA1,BA1, WB1,BB1, W1c,b1c,
                                     Wq2,Wk2,Wv2,Wo2, hh, M3);
    k_fold10_atomic<<<1,128,0,stream>>>(M3, W2a,b2a,g2a,be2a, WA2,BA2);
    k_mid<<<grid256,blk,0,stream>>>(hh, WA2,BA2, W2b,b2b, S4);
    k_fold_big<<<1,256,0,stream>>>(S4, W2b,b2b,g2b,be2b, WB2,BB2);
    k_out<<<grid256,blk,0,stream>>>(hh, WA2,BA2, WB2,BB2, W2c,b2c, (float*)d_out);
  }
}